// Round 1
// baseline (74.603 us; speedup 1.0000x reference)
//
#include <hip/hip_runtime.h>
#include <hip/hip_bf16.h>

// RSA layer, B=64, U=W=128.
// Output only needs i = W-1 row; hj-term and bias cancel in softmax over j.
constexpr int Bx = 64, Ux = 128, Wx = 128;
constexpr int NS = 4;          // v-chunk splits per batch
constexpr int VC = Ux / NS;    // 32 columns per block
constexpr int LDF = 129;       // flip LDS stride (pad: matmul j-stride 4*129 -> 8 distinct banks)
constexpr int LDA = 129;       // a_s stride

__global__ __launch_bounds__(256) void rsa_kernel(const float* __restrict__ input,
                                                  const float* __restrict__ state,
                                                  const float* __restrict__ w,
                                                  float* __restrict__ out) {
  __shared__ float flip_s[Wx][LDF];               // flip[j][u]
  __shared__ float a_s[VC][LDA];                  // sim then a, [v_local][j]
  __shared__ __align__(16) float ws[Ux][VC];      // w_hi chunk [u][v_local]
  __shared__ __align__(16) float wdot_s[VC];
  __shared__ float dot_s[Wx];
  __shared__ float dotp[2][Wx];
  __shared__ float red_s[8][VC];

  const int t = threadIdx.x;
  const int s = blockIdx.x;    // v-chunk index
  const int b = blockIdx.y;    // batch
  const int vbase = s * VC;

  const float* stb = state + (size_t)b * Ux * Wx;
  const float* inb = input + (size_t)b * Ux;

  // ---- stage flip: flip[j][u] = state[b,j,u+1] (u<127) else input[b,j]
  for (int idx = t; idx < Wx * Ux; idx += 256) {
    int j = idx >> 7, u = idx & 127;
    flip_s[j][u] = (u < Wx - 1) ? stb[j * Wx + u + 1] : inb[j];
  }
  // ---- stage w_hi chunk (rows 0..127 of w, cols vbase..vbase+31) and w_dot chunk
  for (int idx = t; idx < Ux * VC; idx += 256) {
    int u = idx >> 5, v = idx & (VC - 1);
    ws[u][v] = w[u * Ux + vbase + v];
  }
  if (t < VC) wdot_s[t] = w[2 * Ux * Ux + vbase + t];
  __syncthreads();

  // ---- dot127[j] = sum_u flip[j][u] * flip[127][u]  (split in 2 u-halves)
  {
    int j = t & 127, h = t >> 7;
    int u0 = h * 64;
    float p = 0.f;
#pragma unroll
    for (int u = 0; u < 64; ++u)
      p = fmaf(flip_s[j][u0 + u], flip_s[Wx - 1][u0 + u], p);
    dotp[h][j] = p;
  }
  __syncthreads();
  if (t < Wx) dot_s[t] = dotp[0][t] + dotp[1][t];
  __syncthreads();

  // ---- hi matmul: sim[j][v] = sum_u flip[j][u]*w_hi[u][v] + dot127[j]*w_dot[v]
  // thread tile: 4 j x 4 v.  vgrp = t&7 (v quad), jg = t>>3 (j quad).
  const int vgrp = t & 7;
  const int jg = t >> 3;
  const int j0 = jg * 4;
  float acc[4][4];
#pragma unroll
  for (int a0 = 0; a0 < 4; ++a0)
#pragma unroll
    for (int a1 = 0; a1 < 4; ++a1) acc[a0][a1] = 0.f;

#pragma unroll 4
  for (int u = 0; u < Ux; ++u) {
    float4 wv = *reinterpret_cast<const float4*>(&ws[u][vgrp * 4]);
#pragma unroll
    for (int jj = 0; jj < 4; ++jj) {
      float f = flip_s[j0 + jj][u];
      acc[jj][0] = fmaf(f, wv.x, acc[jj][0]);
      acc[jj][1] = fmaf(f, wv.y, acc[jj][1]);
      acc[jj][2] = fmaf(f, wv.z, acc[jj][2]);
      acc[jj][3] = fmaf(f, wv.w, acc[jj][3]);
    }
  }
  {
    float4 wd = *reinterpret_cast<const float4*>(&wdot_s[vgrp * 4]);
#pragma unroll
    for (int jj = 0; jj < 4; ++jj) {
      float dj = dot_s[j0 + jj];
      a_s[vgrp * 4 + 0][j0 + jj] = fmaf(dj, wd.x, acc[jj][0]);
      a_s[vgrp * 4 + 1][j0 + jj] = fmaf(dj, wd.y, acc[jj][1]);
      a_s[vgrp * 4 + 2][j0 + jj] = fmaf(dj, wd.z, acc[jj][2]);
      a_s[vgrp * 4 + 3][j0 + jj] = fmaf(dj, wd.w, acc[jj][3]);
    }
  }
  __syncthreads();

  // ---- softmax over j (128) per column v; 8 threads per v, 16 j each
  const int v = t & 31, sub = t >> 5;
  const int jb = sub * 16;
  float m = -3.4e38f;
#pragma unroll
  for (int k = 0; k < 16; ++k) m = fmaxf(m, a_s[v][jb + k]);
  red_s[sub][v] = m;
  __syncthreads();
  float M = red_s[0][v];
#pragma unroll
  for (int r = 1; r < 8; ++r) M = fmaxf(M, red_s[r][v]);
  __syncthreads();

  float ssum = 0.f;
#pragma unroll
  for (int k = 0; k < 16; ++k) {
    float e = __expf(a_s[v][jb + k] - M);
    a_s[v][jb + k] = e;
    ssum += e;
  }
  red_s[sub][v] = ssum;
  __syncthreads();
  float S = 0.f;
#pragma unroll
  for (int r = 0; r < 8; ++r) S += red_s[r][v];
  __syncthreads();

  // ---- out[b, vbase+v] = (1/S) * sum_j flip[j][vbase+v] * a[v][j]
  float p = 0.f;
#pragma unroll
  for (int k = 0; k < 16; ++k) {
    int j = jb + k;
    p = fmaf(flip_s[j][vbase + v], a_s[v][j], p);
  }
  red_s[sub][v] = p;
  __syncthreads();
  if (sub == 0) {
    float o = 0.f;
#pragma unroll
    for (int r = 0; r < 8; ++r) o += red_s[r][v];
    out[(size_t)b * Ux + vbase + v] = o / S;
  }
}

extern "C" void kernel_launch(void* const* d_in, const int* in_sizes, int n_in,
                              void* d_out, int out_size, void* d_ws, size_t ws_size,
                              hipStream_t stream) {
  const float* input = (const float*)d_in[0];
  const float* state = (const float*)d_in[1];
  const float* w     = (const float*)d_in[2];
  // d_in[3] (bias) is not needed: it cancels in softmax over j.
  float* out = (float*)d_out;
  dim3 grid(NS, Bx);
  rsa_kernel<<<grid, dim3(256), 0, stream>>>(input, state, w, out);
}

// Round 2
// 66.849 us; speedup vs baseline: 1.1160x; 1.1160x over previous
//
#include <hip/hip_runtime.h>
#include <hip/hip_bf16.h>

// RSA layer, B=64, U=W=128. Only i=W-1 output row needed; hj-term and bias
// cancel inside softmax over j. bf16 MFMA for sim-matmul and dot-matvec.
constexpr int Bx = 64, Ux = 128, Wx = 128;
constexpr int NS = 4;           // v-chunks per batch -> grid 4 x 64 = 256 blocks
constexpr int VC = 32;          // v columns per block
constexpr int LDST = 136;       // st_s row stride (bf16): 272B = 17*16B aligned, uniform banks
constexpr int LDWT = 136;       // wst row stride (bf16)
constexpr int LDA  = 129;       // a_s row stride (f32): odd -> conflict-free softmax reads

typedef __attribute__((ext_vector_type(8))) short s16x8;   // MFMA A/B frag (8 bf16)
typedef __attribute__((ext_vector_type(4))) float fx4;     // MFMA C/D frag

static __device__ __forceinline__ short f2b(float x) {     // f32 -> bf16 RNE
  union { float f; unsigned u; } c; c.f = x;
  unsigned r = c.u + 0x7fffu + ((c.u >> 16) & 1u);
  return (short)(r >> 16);
}
static __device__ __forceinline__ float b2f(short s) {     // bf16 -> f32 exact
  union { unsigned u; float f; } c; c.u = ((unsigned)(unsigned short)s) << 16;
  return c.f;
}

__global__ __launch_bounds__(256) void rsa_kernel(const float* __restrict__ input,
                                                  const float* __restrict__ state,
                                                  const float* __restrict__ w,
                                                  float* __restrict__ out) {
  __shared__ __align__(16) short st_s[Wx][LDST];  // st_s[j][k]=state[j][k], [j][128]=input[j]
  __shared__ __align__(16) short wst[VC][LDWT];   // wst[v][k]=w_hi[k-1][vb+v], wst[v][0]=0
  __shared__ float a_s[VC][LDA];                  // sim then exp(sim-M), [v][j]
  __shared__ float red_s[8][VC];
  __shared__ float wdot_s[VC], w127_s[VC];
  __shared__ float dpart[4];

  const int t = threadIdx.x;
  const int s = blockIdx.x, b = blockIdx.y;
  const int vb = s * VC;
  const float* stb = state + (size_t)b * Ux * Wx;
  const float* inb = input + (size_t)b * Ux;

  // ---- stage state -> bf16 (coalesced float4 loads, aligned b128 LDS writes)
#pragma unroll
  for (int i = 0; i < 4; ++i) {
    int g = i * 4096 + t * 16;          // flat f32 index, 16-aligned
    int j = g >> 7, k = g & 127;
    const float4* src = reinterpret_cast<const float4*>(stb + g);
    float4 x0 = src[0], x1 = src[1], x2 = src[2], x3 = src[3];
    s16x8 p0 = { f2b(x0.x), f2b(x0.y), f2b(x0.z), f2b(x0.w),
                 f2b(x1.x), f2b(x1.y), f2b(x1.z), f2b(x1.w) };
    s16x8 p1 = { f2b(x2.x), f2b(x2.y), f2b(x2.z), f2b(x2.w),
                 f2b(x3.x), f2b(x3.y), f2b(x3.z), f2b(x3.w) };
    *reinterpret_cast<s16x8*>(&st_s[j][k])     = p0;
    *reinterpret_cast<s16x8*>(&st_s[j][k + 8]) = p1;
  }
  if (t < Wx) st_s[t][128] = f2b(inb[t]);
  // ---- stage w_hi rows 0..126 shifted to wst[v][1..127]; row 127 + w_dot in f32
  for (int idx = t; idx < 127 * VC; idx += 256) {
    int r = idx >> 5, v = idx & (VC - 1);
    wst[v][r + 1] = f2b(w[r * Ux + vb + v]);
  }
  if (t < VC) { wst[t][0] = 0; w127_s[t] = w[127 * Ux + vb + t]; }
  else if (t < 2 * VC) { wdot_s[t - VC] = w[2 * Ux * Ux + vb + (t - VC)]; }
  // ---- exact fp32 dot[127] = ||flip_127||^2 (the large diagonal term)
  {
    float part = 0.f;
    if (t < Wx) { float x = (t < Wx - 1) ? stb[127 * Wx + t + 1] : inb[127]; part = x * x; }
#pragma unroll
    for (int off = 32; off; off >>= 1) part += __shfl_down(part, off);
    if ((t & 63) == 0) dpart[t >> 6] = part;
  }
  __syncthreads();

  // ---- MFMA: sim-hi (2 v-tiles) + dot matvec share A-fragments.
  // A: lane row = l&15 (k-contig 8); B: lane "col" = l&15 (k-contig 8);
  // D: col = l&15, row = (l>>4)*4 + r   [guide §3, m89-verified]
  const int wv = t >> 6, l = t & 63, lc = l & 15, lg = l >> 4;
  fx4 accH[2][2] = {};
  fx4 accD[2]    = {};
#pragma unroll
  for (int kt = 0; kt < 4; ++kt) {
    const int ko = kt * 32 + lg * 8;
    s16x8 bd = *reinterpret_cast<const s16x8*>(&st_s[127][ko]);       // broadcast row 127
    s16x8 b0 = *reinterpret_cast<const s16x8*>(&wst[lc][ko]);
    s16x8 b1 = *reinterpret_cast<const s16x8*>(&wst[lc + 16][ko]);
#pragma unroll
    for (int jl = 0; jl < 2; ++jl) {
      const int jt = wv * 2 + jl;
      s16x8 a = *reinterpret_cast<const s16x8*>(&st_s[jt * 16 + lc][ko]);
      accH[jl][0] = __builtin_amdgcn_mfma_f32_16x16x32_bf16(a, b0, accH[jl][0], 0, 0, 0);
      accH[jl][1] = __builtin_amdgcn_mfma_f32_16x16x32_bf16(a, b1, accH[jl][1], 0, 0, 0);
      accD[jl]    = __builtin_amdgcn_mfma_f32_16x16x32_bf16(a, bd, accD[jl],    0, 0, 0);
    }
  }

  // ---- epilogue: fix dot shift terms, add dot*w_dot + input*w_hi[127], write sim
  const float in127  = b2f(st_s[127][128]);
  const float st0127 = b2f(st_s[127][0]);
  const float d127   = dpart[0] + dpart[1] + dpart[2] + dpart[3];
  const float wd0 = wdot_s[lc], wd1 = wdot_s[lc + 16];
  const float w70 = w127_s[lc], w71 = w127_s[lc + 16];
#pragma unroll
  for (int jl = 0; jl < 2; ++jl) {
    const int jt = wv * 2 + jl;
#pragma unroll
    for (int r = 0; r < 4; ++r) {
      const int row = jt * 16 + lg * 4 + r;
      float st0 = b2f(st_s[row][0]);
      float inr = b2f(st_s[row][128]);
      float dotv = accD[jl][r] - st0 * st0127 + inr * in127;
      if (row == Wx - 1) dotv = d127;                  // exact fp32 diagonal
      a_s[lc][row]      = accH[jl][0][r] + dotv * wd0 + inr * w70;
      a_s[lc + 16][row] = accH[jl][1][r] + dotv * wd1 + inr * w71;
    }
  }
  __syncthreads();

  // ---- softmax over j per column v (8 threads/v, 16 j each)
  const int v = t & 31, sub = t >> 5;
  const int jb = sub * 16;
  float m = -3.4e38f;
#pragma unroll
  for (int k = 0; k < 16; ++k) m = fmaxf(m, a_s[v][jb + k]);
  red_s[sub][v] = m;
  __syncthreads();
  float M = red_s[0][v];
#pragma unroll
  for (int r = 1; r < 8; ++r) M = fmaxf(M, red_s[r][v]);
  __syncthreads();
  float ssum = 0.f;
#pragma unroll
  for (int k = 0; k < 16; ++k) {
    float e = __expf(a_s[v][jb + k] - M);
    a_s[v][jb + k] = e;
    ssum += e;
  }
  red_s[sub][v] = ssum;
  __syncthreads();
  float S = 0.f;
#pragma unroll
  for (int r = 0; r < 8; ++r) S += red_s[r][v];
  __syncthreads();

  // ---- out[b, vb+v] = (1/S) * sum_j flip[j][vb+v] * a[v][j]
  float p = 0.f;
#pragma unroll
  for (int k = 0; k < 16; ++k) {
    int j = jb + k;
    p = fmaf(b2f(st_s[j][vb + v + 1]), a_s[v][j], p);
  }
  red_s[sub][v] = p;
  __syncthreads();
  if (sub == 0) {
    float o = 0.f;
#pragma unroll
    for (int r = 0; r < 8; ++r) o += red_s[r][v];
    out[(size_t)b * Ux + vb + v] = o / S;
  }
}

extern "C" void kernel_launch(void* const* d_in, const int* in_sizes, int n_in,
                              void* d_out, int out_size, void* d_ws, size_t ws_size,
                              hipStream_t stream) {
  const float* input = (const float*)d_in[0];
  const float* state = (const float*)d_in[1];
  const float* w     = (const float*)d_in[2];
  // d_in[3] (bias) not needed: cancels in softmax over j.
  float* out = (float*)d_out;
  dim3 grid(NS, Bx);
  rsa_kernel<<<grid, dim3(256), 0, stream>>>(input, state, w, out);
}